// Round 3
// baseline (746.393 us; speedup 1.0000x reference)
//
#include <hip/hip_runtime.h>
#include <hip/hip_bf16.h>

// MultiScaleFeatureExtractor on MI355X (gfx950) — Round 3
// Math restructuring (unchanged):
//   logits = x @ (Wx@Wslice) + (bx@Wslice + bslice)      (px never materialized)
//   out[s,d] = (sum_n w[n,s]*fx[n,d]) / (sum_n w[n,s] + 0.01)
// R3 changes vs R2:
//   - main2: __launch_bounds__(512,4) -> true 2 blocks/CU (R2's (512,2) only
//     guaranteed 1: 2nd arg is waves/EU, k = w*4/(B/64)).
//   - main2: wT/fT double-buffered (1 barrier/chunk instead of 2) with
//     pitch-128 rows + XOR-swizzled 16B cells -> conflict-free b128 reads.
//   - main2: softmax without max-subtraction (logits/temp bounded |v|<~3 by
//     weight-scale construction; softmax is shift-invariant; fp32 exp safe).
//   - xprep: LDS-transpose version, fully coalesced global on both sides.
//   - prep2: 129 blocks (was 65).
//
// Fast-path ws layout (needs 67,901,440 B; falls back to R1 path otherwise):
//   [0,        67108864)  xf   bf16 A-frags [tile(256)][chunk(8)][tw(4)][ks(8)][lane(64)][j(8)]
//   [67108864, 67633152)  WtF  bf16 B-frags [proj(2)][head(8)][nt(4)][ks(8)][lane(64)][j(8)]
//   [67633152, 67635200)  bc   f32 [512]
//   [67635200, 67897344)  Tg   f32 [B*8*64*64]
//   [67897344, 67901440)  ng   f32 [B*8*64]

typedef __attribute__((ext_vector_type(8))) short short8;
typedef __attribute__((ext_vector_type(4))) short short4v;
typedef __attribute__((ext_vector_type(4))) float float4v;

#define WPITCH 264   // v1 fallback LDS pitch
#define TPITCH 72    // v1 fallback wT/fT pitch

__device__ __forceinline__ unsigned short f2bf(float f) {
    union { float f; unsigned int u; } v; v.f = f;
    unsigned int r = (v.u + 0x7FFFu + ((v.u >> 16) & 1u)) >> 16;  // RNE
    return (unsigned short)r;
}

// ================= Round-3 fast path =================

// ---- xprep: fp32 x -> bf16 A-fragment order via LDS transpose.
// grid 2048 (= tile*8+chunk, 64 tokens each) x 256 threads.
// Read: full token rows, lane-contiguous float4 (perfectly coalesced).
// Write: frag-order, lane-contiguous 16B (perfectly coalesced).
__global__ __launch_bounds__(256)
void msfe_xprep(const float* __restrict__ x, unsigned short* __restrict__ xf) {
    __shared__ unsigned short Xs[64 * WPITCH];
    const int blk = blockIdx.x;
    const int tid = threadIdx.x;
    const float4v* xg = (const float4v*)(x + (long)blk * 64 * 256);
    #pragma unroll
    for (int i = 0; i < 16; ++i) {
        float4v v = xg[tid + i * 256];
        int f = (tid + i * 256) * 4;       // flat float index in 64x256 tile
        int row = f >> 8, col = f & 255;
        short4v p;
        p.x = (short)f2bf(v.x); p.y = (short)f2bf(v.y);
        p.z = (short)f2bf(v.z); p.w = (short)f2bf(v.w);
        *(short4v*)(Xs + row * WPITCH + col) = p;
    }
    __syncthreads();
    const int tw = tid >> 6, lane = tid & 63;
    const int quad = lane >> 4, l16 = lane & 15;
    unsigned short* ob = xf + (((long)blk * 4 + tw) * 8) * 512 + (long)lane * 8;
    #pragma unroll
    for (int ks = 0; ks < 8; ++ks) {
        short8 o = *(const short8*)(Xs + (tw * 16 + l16) * WPITCH + ks * 32 + quad * 8);
        *(short8*)(ob + ks * 512) = o;     // coalesced 1KB/instr
    }
}

// ---- prep2: fold Wx@Wslice + reformat Wfx into B-fragment order; compute bc.
// grid 129 x 256. blocks 0..127: (p, proj, head, nt); block 128: bc.
__global__ void msfe_prep2(const float* __restrict__ Wx, const float* __restrict__ bx,
                           const float* __restrict__ Wfx,
                           const float* __restrict__ Wslice, const float* __restrict__ bslice,
                           unsigned short* __restrict__ WtF, float* __restrict__ bcv) {
    const int blk = blockIdx.x, tid = threadIdx.x;
    if (blk < 128) {
        const int p = blk & 1, b = blk >> 1;
        const int proj = b >> 5, hb = b & 31, head = hb >> 2, nt = hb & 3;
        int idx = tid + p * 256;            // 0..511 = (ks, lane)
        int ks = idx >> 6, l = idx & 63;
        int quad = l >> 4, l16 = l & 15;
        unsigned short* out = WtF + ((((long)(proj * 8 + head) * 4 + nt) * 8 + ks) * 64 + l) * 8;
        if (proj == 0) {
            int s = nt * 16 + l16;
            #pragma unroll
            for (int j = 0; j < 8; ++j) {
                int k = ks * 32 + quad * 8 + j;
                const float* wr = Wx + k * 512 + head * 64;
                float a0 = 0.f, a1 = 0.f;
                #pragma unroll 8
                for (int d = 0; d < 64; d += 2) {
                    a0 += wr[d]     * Wslice[d * 64 + s];
                    a1 += wr[d + 1] * Wslice[(d + 1) * 64 + s];
                }
                out[j] = f2bf(a0 + a1);
            }
        } else {
            int col = head * 64 + nt * 16 + l16;
            #pragma unroll
            for (int j = 0; j < 8; ++j) {
                int k = ks * 32 + quad * 8 + j;
                out[j] = f2bf(Wfx[k * 512 + col]);
            }
        }
    } else {
        #pragma unroll
        for (int p = 0; p < 2; ++p) {
            int j = tid + p * 256;
            int h = j >> 6, s = j & 63;
            float bsum = bslice[s];
            for (int d = 0; d < 64; ++d) bsum += bx[h * 64 + d] * Wslice[d * 64 + s];
            bcv[j] = bsum;
        }
    }
}

// ---- main2: weights in registers, A-frags from global, LDS only for transpose.
// wT/fT: 64 rows x 8 cells of 16B, physical cell = cell ^ (row&7)  -> zero bank
// conflicts on both the 8B P2 writes and the b128 P3 reads (verified bank math).
__global__ __launch_bounds__(512, 4)
void msfe_main2(const unsigned short* __restrict__ xf,
                const unsigned short* __restrict__ WtF,
                const float* __restrict__ bcv,
                const float* __restrict__ bfx,
                const float* __restrict__ temperature,
                float* __restrict__ Tg, float* __restrict__ ng) {
    __shared__ unsigned short wT[2][64 * 128];
    __shared__ unsigned short fT[2][64 * 128];

    const int tid  = threadIdx.x;
    const int lane = tid & 63;
    const int wv   = tid >> 6;    // 0..7
    const int quad = lane >> 4;
    const int l16  = lane & 15;

    // blockIdx -> (round, xcd, tileInXcd, head): same-tile heads share an XCD round
    const int bidx = blockIdx.x;
    const int c8   = bidx & 7;
    const int ti   = (bidx >> 3) & 3;
    const int head = (bidx >> 5) & 7;
    const int rnd  = bidx >> 8;
    const int tile = rnd * 32 + c8 * 4 + ti;      // 0..255
    const int batch = tile >> 7;

    const int proj = wv >> 2;   // 0: logits+softmax waves, 1: fx waves
    const int tw   = wv & 3;    // P1 token sub-tile
    const int sh   = wv & 3;    // P3 s-tile
    const int dh   = wv >> 2;   // P3 d-half

    // ---- weight fragments -> registers (once per block, coalesced 1KB loads)
    short8 wfr[4][8];
    {
        const unsigned short* wb = WtF + (((long)(proj * 8 + head) * 4) * 8) * 512 + lane * 8;
        #pragma unroll
        for (int nt = 0; nt < 4; ++nt)
            #pragma unroll
            for (int ks = 0; ks < 8; ++ks)
                wfr[nt][ks] = *(const short8*)(wb + (nt * 8 + ks) * 512);
    }

    float bcr[4], bfxr[4];
    #pragma unroll
    for (int nt = 0; nt < 4; ++nt) {
        bcr[nt]  = bcv[head * 64 + nt * 16 + l16];
        bfxr[nt] = bfx[head * 64 + nt * 16 + l16];
    }
    float tmp = temperature[head];
    tmp = fminf(fmaxf(tmp, 0.5f), 5.0f);
    const float invt = 1.0f / tmp;

    float4v Tac[2];
    Tac[0] = (float4v){0.f, 0.f, 0.f, 0.f};
    Tac[1] = (float4v){0.f, 0.f, 0.f, 0.f};
    float normAcc[4] = {0.f, 0.f, 0.f, 0.f};

    // ---- A-frag preload chunk 0
    const unsigned short* xb = xf + ((long)tile * 8 * 4 * 8) * 512 + (long)lane * 8;
    short8 afr[8];
    #pragma unroll
    for (int ks = 0; ks < 8; ++ks)
        afr[ks] = *(const short8*)(xb + ((0 * 4 + tw) * 8 + ks) * 512);

    // P2-write swizzle constants
    const int cellw = tw * 2 + (quad >> 1);      // logical 16B cell of this thread's 8B
    const int halfo = (quad & 1) * 4;            // shorts offset within the cell

    for (int c = 0; c < 8; ++c) {
        const int buf = c & 1;

        // P1: [16 tok x 64 cols] += A(x) * B(weights-in-regs), K=256
        float4v acc[4];
        #pragma unroll
        for (int nt = 0; nt < 4; ++nt) acc[nt] = (float4v){0.f, 0.f, 0.f, 0.f};
        #pragma unroll
        for (int ks = 0; ks < 8; ++ks) {
            #pragma unroll
            for (int nt = 0; nt < 4; ++nt)
                acc[nt] = __builtin_amdgcn_mfma_f32_16x16x32_bf16(afr[ks], wfr[nt][ks], acc[nt], 0, 0, 0);
        }

        // prefetch next chunk's A-frags (latency hidden behind P2+barrier+P3)
        if (c < 7) {
            #pragma unroll
            for (int ks = 0; ks < 8; ++ks)
                afr[ks] = *(const short8*)(xb + (((c + 1) * 4 + tw) * 8 + ks) * 512);
        }

        // P2: softmax (proj 0) / bias (proj 1), write transposed bf16 to LDS.
        // C layout: col=l16+16*nt, row=quad*4+r -> token = 16*tw + quad*4 + r
        if (proj == 0) {
            float e[4][4];
            #pragma unroll
            for (int nt = 0; nt < 4; ++nt)
                #pragma unroll
                for (int r = 0; r < 4; ++r)
                    e[nt][r] = __expf((acc[nt][r] + bcr[nt]) * invt);  // |arg|<~6: safe, shift-free
            #pragma unroll
            for (int r = 0; r < 4; ++r) {
                float s = e[0][r] + e[1][r] + e[2][r] + e[3][r];
                s += __shfl_xor(s, 1); s += __shfl_xor(s, 2);
                s += __shfl_xor(s, 4); s += __shfl_xor(s, 8);
                float inv = 1.0f / s;
                e[0][r] *= inv; e[1][r] *= inv; e[2][r] *= inv; e[3][r] *= inv;
            }
            #pragma unroll
            for (int nt = 0; nt < 4; ++nt) {
                normAcc[nt] += e[nt][0] + e[nt][1] + e[nt][2] + e[nt][3];
                short4v p;
                p.x = (short)f2bf(e[nt][0]); p.y = (short)f2bf(e[nt][1]);
                p.z = (short)f2bf(e[nt][2]); p.w = (short)f2bf(e[nt][3]);
                *(short4v*)(&wT[buf][(nt * 16 + l16) * 128 + ((cellw ^ (l16 & 7)) * 8) + halfo]) = p;
            }
        } else {
            #pragma unroll
            for (int nt = 0; nt < 4; ++nt) {
                short4v p;
                p.x = (short)f2bf(acc[nt][0] + bfxr[nt]);
                p.y = (short)f2bf(acc[nt][1] + bfxr[nt]);
                p.z = (short)f2bf(acc[nt][2] + bfxr[nt]);
                p.w = (short)f2bf(acc[nt][3] + bfxr[nt]);
                *(short4v*)(&fT[buf][(nt * 16 + l16) * 128 + ((cellw ^ (l16 & 7)) * 8) + halfo]) = p;
            }
        }

        __syncthreads();   // the ONLY barrier per chunk (double-buffered wT/fT)

        // P3: T[s][d] += w^T fx over 64 chunk tokens. wave: 16 s x 32 d.
        #pragma unroll
        for (int ks = 0; ks < 2; ++ks) {
            int ca = (ks * 4 + quad) ^ (l16 & 7);
            short8 a = *(const short8*)(&wT[buf][(sh * 16 + l16) * 128 + ca * 8]);
            #pragma unroll
            for (int nt = 0; nt < 2; ++nt) {
                int cb = (ks * 4 + quad) ^ (l16 & 7);
                short8 b = *(const short8*)(&fT[buf][(dh * 32 + nt * 16 + l16) * 128 + cb * 8]);
                Tac[nt] = __builtin_amdgcn_mfma_f32_16x16x32_bf16(a, b, Tac[nt], 0, 0, 0);
            }
        }
    }

    // epilogue: atomics into global accumulators
    const int basehs = (batch * 8 + head) * 64;
    #pragma unroll
    for (int nt = 0; nt < 2; ++nt) {
        #pragma unroll
        for (int r = 0; r < 4; ++r) {
            int s = sh * 16 + quad * 4 + r;
            int d = dh * 32 + nt * 16 + l16;
            atomicAdd(&Tg[(basehs + s) * 64 + d], Tac[nt][r]);
        }
    }
    if (wv < 4) {
        #pragma unroll
        for (int nt = 0; nt < 4; ++nt) {
            float v = normAcc[nt];
            v += __shfl_xor(v, 16);
            v += __shfl_xor(v, 32);
            if (quad == 0) atomicAdd(&ng[basehs + nt * 16 + l16], v);
        }
    }
}

// ================= Round-1 fallback path (unchanged, known-correct) =================

__global__ void msfe_prep(const float* __restrict__ Wx, const float* __restrict__ bx,
                          const float* __restrict__ Wfx,
                          const float* __restrict__ Wslice, const float* __restrict__ bslice,
                          unsigned short* __restrict__ Wt, float* __restrict__ bc) {
    int j = blockIdx.x;
    int c = threadIdx.x;
    if (j < 512) {
        int h = j >> 6, s = j & 63;
        float acc = 0.f;
        #pragma unroll 8
        for (int d = 0; d < 64; ++d)
            acc += Wx[c * 512 + h * 64 + d] * Wslice[d * 64 + s];
        Wt[j * 256 + c] = f2bf(acc);
        if (c == 0) {
            float b = bslice[s];
            for (int d = 0; d < 64; ++d) b += bx[h * 64 + d] * Wslice[d * 64 + s];
            bc[j] = b;
        }
    } else {
        int col = j - 512;
        Wt[j * 256 + c] = f2bf(Wfx[c * 512 + col]);
    }
}

__global__ __launch_bounds__(512, 2)
void msfe_main(const float* __restrict__ x,
               const unsigned short* __restrict__ Wt,
               const float* __restrict__ bc,
               const float* __restrict__ bfx,
               const float* __restrict__ temperature,
               float* __restrict__ Tg, float* __restrict__ ng) {
    __shared__ unsigned short Ws[128 * WPITCH];
    __shared__ unsigned short Xs[64 * WPITCH];
    __shared__ unsigned short wT[64 * TPITCH];
    __shared__ unsigned short fT[64 * TPITCH];

    const int tid  = threadIdx.x;
    const int lane = tid & 63;
    const int wv   = tid >> 6;
    const int quad = lane >> 4;
    const int l16  = lane & 15;

    const int bidx = blockIdx.x;
    const int c8   = bidx & 7;
    const int ti   = (bidx >> 3) & 3;
    const int head = (bidx >> 5) & 7;
    const int rnd  = bidx >> 8;
    const int tile = rnd * 32 + c8 * 4 + ti;
    const int batch = tile >> 7;
    const long tok0 = (long)tile * 512;

    {
        int r = tid & 127;
        int part = tid >> 7;
        int grow = (r < 64) ? (head * 64 + r) : (512 + head * 64 + (r - 64));
        const short4v* src = (const short4v*)(Wt + grow * 256 + part * 64);
        short4v* dst = (short4v*)(Ws + r * WPITCH + part * 64);
        #pragma unroll
        for (int j = 0; j < 16; ++j) dst[j] = src[j];
    }
    {
        const float4v* xg = (const float4v*)(x + tok0 * 256);
        #pragma unroll
        for (int i = 0; i < 8; ++i) {
            float4v v = xg[tid + i * 512];
            int f = (tid + i * 512) * 4;
            int trow = f >> 8, col = f & 255;
            short4v p;
            p.x = (short)f2bf(v.x); p.y = (short)f2bf(v.y);
            p.z = (short)f2bf(v.z); p.w = (short)f2bf(v.w);
            *(short4v*)(Xs + trow * WPITCH + col) = p;
        }
    }

    float bcr[4], bfxr[4];
    #pragma unroll
    for (int nt = 0; nt < 4; ++nt) {
        bcr[nt]  = bc [head * 64 + nt * 16 + l16];
        bfxr[nt] = bfx[head * 64 + nt * 16 + l16];
    }
    float tmp = temperature[head];
    tmp = fminf(fmaxf(tmp, 0.5f), 5.0f);
    const float invt = 1.0f / tmp;

    float4v Tac[2];
    Tac[0] = (float4v){0.f, 0.f, 0.f, 0.f};
    Tac[1] = (float4v){0.f, 0.f, 0.f, 0.f};
    float normAcc[4] = {0.f, 0.f, 0.f, 0.f};

    const int proj = wv >> 2;
    const int tw   = wv & 3;
    const int sh   = wv & 3;
    const int dh   = wv >> 2;

    __syncthreads();

    for (int c = 0; c < 8; ++c) {
        float4v xr[8];
        if (c < 7) {
            const float4v* xg = (const float4v*)(x + (tok0 + (long)(c + 1) * 64) * 256);
            #pragma unroll
            for (int i = 0; i < 8; ++i) xr[i] = xg[tid + i * 512];
        }

        float4v acc[4];
        #pragma unroll
        for (int nt = 0; nt < 4; ++nt) acc[nt] = (float4v){0.f, 0.f, 0.f, 0.f};
        #pragma unroll
        for (int ks = 0; ks < 8; ++ks) {
            short8 a = *(const short8*)(Xs + (tw * 16 + l16) * WPITCH + ks * 32 + quad * 8);
            #pragma unroll
            for (int nt = 0; nt < 4; ++nt) {
                short8 b = *(const short8*)(Ws + (proj * 64 + nt * 16 + l16) * WPITCH + ks * 32 + quad * 8);
                acc[nt] = __builtin_amdgcn_mfma_f32_16x16x32_bf16(a, b, acc[nt], 0, 0, 0);
            }
        }

        if (proj == 0) {
            float v[4][4];
            #pragma unroll
            for (int nt = 0; nt < 4; ++nt)
                #pragma unroll
                for (int r = 0; r < 4; ++r)
                    v[nt][r] = (acc[nt][r] + bcr[nt]) * invt;
            #pragma unroll
            for (int r = 0; r < 4; ++r) {
                float m = fmaxf(fmaxf(v[0][r], v[1][r]), fmaxf(v[2][r], v[3][r]));
                m = fmaxf(m, __shfl_xor(m, 1));
                m = fmaxf(m, __shfl_xor(m, 2));
                m = fmaxf(m, __shfl_xor(m, 4));
                m = fmaxf(m, __shfl_xor(m, 8));
                float e0 = __expf(v[0][r] - m), e1 = __expf(v[1][r] - m);
                float e2 = __expf(v[2][r] - m), e3 = __expf(v[3][r] - m);
                float s = e0 + e1 + e2 + e3;
                s += __shfl_xor(s, 1); s += __shfl_xor(s, 2);
                s += __shfl_xor(s, 4); s += __shfl_xor(s, 8);
                float inv = 1.0f / s;
                v[0][r] = e0 * inv; v[1][r] = e1 * inv; v[2][r] = e2 * inv; v[3][r] = e3 * inv;
            }
            #pragma unroll
            for (int nt = 0; nt < 4; ++nt) {
                normAcc[nt] += v[nt][0] + v[nt][1] + v[nt][2] + v[nt][3];
                short4v p;
                p.x = (short)f2bf(v[nt][0]); p.y = (short)f2bf(v[nt][1]);
                p.z = (short)f2bf(v[nt][2]); p.w = (short)f2bf(v[nt][3]);
                *(short4v*)(wT + (nt * 16 + l16) * TPITCH + tw * 16 + quad * 4) = p;
            }
        } else {
            #pragma unroll
            for (int nt = 0; nt < 4; ++nt) {
                short4v p;
                p.x = (short)f2bf(acc[nt][0] + bfxr[nt]);
                p.y = (short)f2bf(acc[nt][1] + bfxr[nt]);
                p.z = (short)f2bf(acc[nt][2] + bfxr[nt]);
                p.w = (short)f2bf(acc[nt][3] + bfxr[nt]);
                *(short4v*)(fT + (nt * 16 + l16) * TPITCH + tw * 16 + quad * 4) = p;
            }
        }

        __syncthreads();

        #pragma unroll
        for (int ks = 0; ks < 2; ++ks) {
            short8 a = *(const short8*)(wT + (sh * 16 + l16) * TPITCH + ks * 32 + quad * 8);
            #pragma unroll
            for (int nt = 0; nt < 2; ++nt) {
                short8 b = *(const short8*)(fT + (dh * 32 + nt * 16 + l16) * TPITCH + ks * 32 + quad * 8);
                Tac[nt] = __builtin_amdgcn_mfma_f32_16x16x32_bf16(a, b, Tac[nt], 0, 0, 0);
            }
        }

        if (c < 7) {
            #pragma unroll
            for (int i = 0; i < 8; ++i) {
                int f = tid * 4 + i * 2048;
                int trow = f >> 8, col = f & 255;
                short4v p;
                p.x = (short)f2bf(xr[i].x); p.y = (short)f2bf(xr[i].y);
                p.z = (short)f2bf(xr[i].z); p.w = (short)f2bf(xr[i].w);
                *(short4v*)(Xs + trow * WPITCH + col) = p;
            }
        }
        __syncthreads();
    }

    const int basehs = (batch * 8 + head) * 64;
    #pragma unroll
    for (int nt = 0; nt < 2; ++nt) {
        #pragma unroll
        for (int r = 0; r < 4; ++r) {
            int s = sh * 16 + quad * 4 + r;
            int d = dh * 32 + nt * 16 + l16;
            atomicAdd(&Tg[(basehs + s) * 64 + d], Tac[nt][r]);
        }
    }
    if (wv < 4) {
        #pragma unroll
        for (int nt = 0; nt < 4; ++nt) {
            float v = normAcc[nt];
            v += __shfl_xor(v, 16);
            v += __shfl_xor(v, 32);
            if (quad == 0) atomicAdd(&ng[basehs + nt * 16 + l16], v);
        }
    }
}

// ---------------- finalize ----------------
__global__ void msfe_final(const float* __restrict__ Tg, const float* __restrict__ ng,
                           float* __restrict__ out) {
    int i = blockIdx.x * 256 + threadIdx.x;
    out[i] = Tg[i] / (ng[i >> 6] + 0.01f);
}

extern "C" void kernel_launch(void* const* d_in, const int* in_sizes, int n_in,
                              void* d_out, int out_size, void* d_ws, size_t ws_size,
                              hipStream_t stream) {
    const float* x       = (const float*)d_in[0];
    const float* Wx      = (const float*)d_in[1];
    const float* bx      = (const float*)d_in[2];
    const float* Wfx     = (const float*)d_in[3];
    const float* bfx     = (const float*)d_in[4];
    const float* Wslice  = (const float*)d_in[5];
    const float* bslice  = (const float*)d_in[6];
    const float* temp    = (const float*)d_in[7];

    char* ws = (char*)d_ws;
    const size_t NEED = 67901440;   // xf 64MB + WtF 512KB + bc 2KB + Tg 256KB + ng 4KB

    if (ws_size >= NEED) {
        unsigned short* xf  = (unsigned short*)ws;               // 67,108,864 B
        unsigned short* WtF = (unsigned short*)(ws + 67108864);  //    524,288 B
        float* bc = (float*)(ws + 67633152);                     //      2,048 B
        float* Tg = (float*)(ws + 67635200);                     //    262,144 B
        float* ng = (float*)(ws + 67897344);                     //      4,096 B

        hipMemsetAsync(Tg, 0, 262144 + 4096, stream);
        msfe_prep2<<<129, 256, 0, stream>>>(Wx, bx, Wfx, Wslice, bslice, WtF, bc);
        msfe_xprep<<<2048, 256, 0, stream>>>(x, xf);
        msfe_main2<<<2048, 512, 0, stream>>>(xf, WtF, bc, bfx, temp, Tg, ng);
        msfe_final<<<256, 256, 0, stream>>>(Tg, ng, (float*)d_out);
    } else {
        unsigned short* Wt = (unsigned short*)ws;       // 524,288 B
        float* bc = (float*)(ws + 524288);
        float* Tg = (float*)(ws + 526336);
        float* ng = (float*)(ws + 788480);

        hipMemsetAsync(Tg, 0, 262144 + 4096, stream);
        msfe_prep<<<1024, 256, 0, stream>>>(Wx, bx, Wfx, Wslice, bslice, Wt, bc);
        msfe_main<<<2048, 512, 0, stream>>>(x, Wt, bc, bfx, temp, Tg, ng);
        msfe_final<<<256, 256, 0, stream>>>(Tg, ng, (float*)d_out);
    }
}

// Round 4
// 343.086 us; speedup vs baseline: 2.1755x; 2.1755x over previous
//
#include <hip/hip_runtime.h>
#include <hip/hip_bf16.h>

// MultiScaleFeatureExtractor on MI355X (gfx950) — Round 4
// Math restructuring (unchanged):
//   logits = x @ (Wx@Wslice) + (bx@Wslice + bslice)      (px never materialized)
//   out[s,d] = (sum_n w[n,s]*fx[n,d]) / (sum_n w[n,s] + 0.01)
// R4 vs R2/R3:
//   - main3: 256-thread blocks (4 waves), 4096 blocks, 32-token chunks ->
//     ~220 regs/wave fits 2 waves/EU -> 2 INDEPENDENT blocks/CU (R3 tried this
//     with 512-thread blocks and spilled: VGPR capped 128 < 220 needed).
//   - main3: skewed pipeline: P3 consumes previous chunk's LDS buffer ->
//     P1+P3 MFMA adjacent, ONE barrier per chunk.
//   - prep3: Wslice in LDS (broadcast b128), Wx rows in VGPRs, LDS-transpose
//     frag-order output. Replaces the ~100us prep2 (512 dependent loads/thread).
//   - hw packed bf16 convert (__float22bfloat162_rn).
//
// Fast-path ws layout (NEED = 67,901,440 B; falls back to R1 path otherwise):
//   [0,        67108864)  xf   bf16 A-frags [tile(512)][chunk(8)][tw(2)][ks(8)][lane(64)][j(8)]
//   [67108864, 67633152)  WtF  bf16 B-frags [proj(2)][head(8)][nt(4)][ks(8)][lane(64)][j(8)]
//   [67633152, 67635200)  bc   f32 [512]
//   [67635200, 67897344)  Tg   f32 [B*8*64*64]
//   [67897344, 67901440)  ng   f32 [B*8*64]

typedef __attribute__((ext_vector_type(8))) short short8;
typedef __attribute__((ext_vector_type(4))) short short4v;
typedef __attribute__((ext_vector_type(4))) float float4v;
typedef __attribute__((ext_vector_type(2))) unsigned int uint2v;

#define WPITCH 264   // xprep / fallback LDS pitch (shorts)
#define TPITCH 72    // fallback wT/fT pitch (shorts)
#define MP 36        // main3 wT/fT pitch: 32-token rows + 4 pad shorts (72B rows)

__device__ __forceinline__ unsigned short f2bf(float f) {
    union { float f; unsigned int u; } v; v.f = f;
    unsigned int r = (v.u + 0x7FFFu + ((v.u >> 16) & 1u)) >> 16;  // RNE
    return (unsigned short)r;
}

__device__ __forceinline__ unsigned int pack2(float a, float b) {
    __hip_bfloat162 h = __float22bfloat162_rn(float2{a, b});
    union { __hip_bfloat162 h; unsigned int u; } cv; cv.h = h;
    return cv.u;   // low 16 bits = a, high = b
}

// ================= Round-4 fast path =================

// ---- xprep: fp32 x -> bf16 A-frag order. 2048 blocks x 256 thr, 64 tokens/block.
__global__ __launch_bounds__(256)
void msfe_xprep(const float* __restrict__ x, unsigned short* __restrict__ xf) {
    __shared__ unsigned short Xs[64 * WPITCH];
    const int blk = blockIdx.x;
    const int tid = threadIdx.x;
    const float4v* xg = (const float4v*)(x + (long)blk * 64 * 256);
    #pragma unroll
    for (int i = 0; i < 16; ++i) {
        float4v v = xg[tid + i * 256];
        int f = (tid + i * 256) * 4;       // flat float index in 64x256 tile
        int row = f >> 8, col = f & 255;
        unsigned int lo = pack2(v.x, v.y), hi = pack2(v.z, v.w);
        *(unsigned int*)(Xs + row * WPITCH + col)     = lo;
        *(unsigned int*)(Xs + row * WPITCH + col + 2) = hi;
    }
    __syncthreads();
    const int wv = tid >> 6, lane = tid & 63;
    const int quad = lane >> 4, l16 = lane & 15;
    const int chunkL = wv >> 1, tw = wv & 1;       // block covers 2 chunks of 32 tok
    const int tile = blk >> 2;
    const int chunk = (blk & 3) * 2 + chunkL;
    unsigned short* ob = xf + ((((long)tile * 8 + chunk) * 2 + tw) * 8) * 512 + (long)lane * 8;
    const int row0 = chunkL * 32 + tw * 16 + l16;
    #pragma unroll
    for (int ks = 0; ks < 8; ++ks) {
        short8 o = *(const short8*)(Xs + row0 * WPITCH + ks * 32 + quad * 8);
        *(short8*)(ob + ks * 512) = o;     // coalesced 1KB/instr
    }
}

// ---- prep3: fold Wx@Wslice + reformat Wfx into B-frag order; compute bc.
// grid 49 x 256: b 0..31 proj0 (head,kq,sg), 32..47 proj1 (head,kq), 48 bc.
__global__ __launch_bounds__(256)
void msfe_prep3(const float* __restrict__ Wx, const float* __restrict__ bx,
                const float* __restrict__ Wfx,
                const float* __restrict__ Wslice, const float* __restrict__ bslice,
                unsigned short* __restrict__ WtF, float* __restrict__ bcv) {
    const int b = blockIdx.x, t = threadIdx.x;
    if (b < 32) {
        // proj0: block (head, kq, sg): k in [kq*128,+128), s in [sg*32,+32)
        const int head = b >> 2, kq = (b >> 1) & 1, sg = b & 1;
        __shared__ float Wsl[64 * 68];
        __shared__ unsigned short stg[128 * 33];
        #pragma unroll
        for (int i = 0; i < 16; ++i) {
            int idx = i * 256 + t; int d = idx >> 6, s = idx & 63;
            Wsl[d * 68 + s] = Wslice[idx];
        }
        const int kl = t & 127, sHalf = t >> 7;     // wave-uniform sHalf
        const int k = kq * 128 + kl;
        float wxr[64];
        const float4v* src = (const float4v*)(Wx + (long)k * 512 + head * 64);
        #pragma unroll
        for (int i = 0; i < 16; ++i) {
            float4v v = src[i];
            wxr[i*4+0] = v.x; wxr[i*4+1] = v.y; wxr[i*4+2] = v.z; wxr[i*4+3] = v.w;
        }
        __syncthreads();
        const int sbase = sg * 32 + sHalf * 16;
        float acc[16];
        #pragma unroll
        for (int si = 0; si < 16; ++si) acc[si] = 0.f;
        #pragma unroll
        for (int d = 0; d < 64; ++d) {
            float w = wxr[d];
            const float4v* r4 = (const float4v*)(Wsl + d * 68 + sbase);  // broadcast b128
            float4v v0 = r4[0], v1 = r4[1], v2 = r4[2], v3 = r4[3];
            acc[0]  += w * v0.x; acc[1]  += w * v0.y; acc[2]  += w * v0.z; acc[3]  += w * v0.w;
            acc[4]  += w * v1.x; acc[5]  += w * v1.y; acc[6]  += w * v1.z; acc[7]  += w * v1.w;
            acc[8]  += w * v2.x; acc[9]  += w * v2.y; acc[10] += w * v2.z; acc[11] += w * v2.w;
            acc[12] += w * v3.x; acc[13] += w * v3.y; acc[14] += w * v3.z; acc[15] += w * v3.w;
        }
        #pragma unroll
        for (int si = 0; si < 16; ++si)
            stg[kl * 33 + sHalf * 16 + si] = f2bf(acc[si]);
        __syncthreads();
        // frag-order write: e = [ntL(2)][ksL(4)][lane(64)]
        #pragma unroll
        for (int i = 0; i < 2; ++i) {
            int e = i * 256 + t;
            int ntL = e >> 8, ksL = (e >> 6) & 3, lane = e & 63;
            int quad = lane >> 4, l16 = lane & 15;
            int nt = sg * 2 + ntL;
            int ks = kq * 4 + ksL;
            short8 o;
            #pragma unroll
            for (int j = 0; j < 8; ++j) {
                int kl2 = ksL * 32 + quad * 8 + j;
                o[j] = (short)stg[kl2 * 33 + ntL * 16 + l16];
            }
            *(short8*)(WtF + ((((long)(0 * 8 + head) * 4 + nt) * 8 + ks) * 64 + lane) * 8) = o;
        }
    } else if (b < 48) {
        // proj1: pure reformat of Wfx
        const int head = (b - 32) >> 1, kq = (b - 32) & 1;
        #pragma unroll
        for (int i = 0; i < 4; ++i) {
            int e = i * 256 + t;
            int nt = e >> 8, ksL = (e >> 6) & 3, lane = e & 63;
            int quad = lane >> 4, l16 = lane & 15;
            int ks = kq * 4 + ksL;
            int col = head * 64 + nt * 16 + l16;
            short8 o;
            #pragma unroll
            for (int j = 0; j < 8; ++j) {
                int k = kq * 128 + ksL * 32 + quad * 8 + j;
                o[j] = (short)f2bf(Wfx[(long)k * 512 + col]);
            }
            *(short8*)(WtF + ((((long)(1 * 8 + head) * 4 + nt) * 8 + ks) * 64 + lane) * 8) = o;
        }
    } else {
        #pragma unroll
        for (int p = 0; p < 2; ++p) {
            int j = t + p * 256;
            int h = j >> 6, s = j & 63;
            float bsum = bslice[s];
            for (int d = 0; d < 64; ++d) bsum += bx[h * 64 + d] * Wslice[d * 64 + s];
            bcv[j] = bsum;
        }
    }
}

// ---- main3: 4096 blocks x 256 thr (4 waves), 32-token chunks, skewed P3.
__global__ __launch_bounds__(256, 2)
void msfe_main3(const unsigned short* __restrict__ xf,
                const unsigned short* __restrict__ WtF,
                const float* __restrict__ bcv,
                const float* __restrict__ bfx,
                const float* __restrict__ temperature,
                float* __restrict__ Tg, float* __restrict__ ng) {
    __shared__ unsigned short wT[2][64 * MP];   // [s][token] bf16, double-buffered
    __shared__ unsigned short fT[2][64 * MP];   // [d][token]

    const int tid  = threadIdx.x;
    const int lane = tid & 63;
    const int wv   = tid >> 6;    // 0..3
    const int quad = lane >> 4;
    const int l16  = lane & 15;

    // bidx -> (r, xcd, tileInXcd, head): a tile's 8 heads share an XCD round
    const int bidx = blockIdx.x;
    const int xcd  = bidx & 7;
    const int i5   = (bidx >> 3) & 31;
    const int r    = bidx >> 8;               // 0..15
    const int tile = r * 32 + xcd * 4 + (i5 >> 3);   // 0..511 (256 tokens each)
    const int head = i5 & 7;
    const int batch = tile >> 8;

    const int proj = wv >> 1;   // waves 0,1: logits+softmax; 2,3: fx
    const int tw   = wv & 1;    // 16-token sub-tile within 32-token chunk

    // ---- weight fragments -> registers (once per block)
    short8 wfr[4][8];
    {
        const unsigned short* wb = WtF + (((long)(proj * 8 + head) * 4) * 8) * 512 + (long)lane * 8;
        #pragma unroll
        for (int nt = 0; nt < 4; ++nt)
            #pragma unroll
            for (int ks = 0; ks < 8; ++ks)
                wfr[nt][ks] = *(const short8*)(wb + (nt * 8 + ks) * 512);
    }

    float bcr[4], bfxr[4];
    #pragma unroll
    for (int nt = 0; nt < 4; ++nt) {
        bcr[nt]  = bcv[head * 64 + nt * 16 + l16];
        bfxr[nt] = bfx[head * 64 + nt * 16 + l16];
    }
    float tmp = temperature[head];
    tmp = fminf(fmaxf(tmp, 0.5f), 5.0f);
    const float invt = 1.0f / tmp;

    float4v Tac[4];
    #pragma unroll
    for (int nt = 0; nt < 4; ++nt) Tac[nt] = (float4v){0.f, 0.f, 0.f, 0.f};
    float normAcc[4] = {0.f, 0.f, 0.f, 0.f};

    // A-frag base: [tile][chunk][tw][ks][lane*8]; chunk stride 8192, ks stride 512
    const unsigned short* xb = xf + (((long)tile * 8 * 2 + tw) * 8) * 512 + (long)lane * 8;
    short8 afr[8];
    #pragma unroll
    for (int ks = 0; ks < 8; ++ks)
        afr[ks] = *(const short8*)(xb + ks * 512);

    for (int c = 0; c < 8; ++c) {
        const int wbuf = c & 1, rbuf = wbuf ^ 1;

        // P1: [16 tok x 64 cols] += A(x) * B(w-regs), K=256
        float4v acc[4];
        #pragma unroll
        for (int nt = 0; nt < 4; ++nt) acc[nt] = (float4v){0.f, 0.f, 0.f, 0.f};
        #pragma unroll
        for (int ks = 0; ks < 8; ++ks) {
            #pragma unroll
            for (int nt = 0; nt < 4; ++nt)
                acc[nt] = __builtin_amdgcn_mfma_f32_16x16x32_bf16(afr[ks], wfr[nt][ks], acc[nt], 0, 0, 0);
        }

        // reload A-frags for next chunk (overlaps P2 VALU + barrier)
        if (c < 7) {
            #pragma unroll
            for (int ks = 0; ks < 8; ++ks)
                afr[ks] = *(const short8*)(xb + (long)(c + 1) * 8192 + ks * 512);
        }

        // P3 (skewed): T[s][d] += w^T fx over PREVIOUS chunk's 32 tokens.
        if (c > 0) {
            short8 a = *(const short8*)(&wT[rbuf][(wv * 16 + l16) * MP + quad * 8]);
            #pragma unroll
            for (int nt = 0; nt < 4; ++nt) {
                short8 bf = *(const short8*)(&fT[rbuf][(nt * 16 + l16) * MP + quad * 8]);
                Tac[nt] = __builtin_amdgcn_mfma_f32_16x16x32_bf16(a, bf, Tac[nt], 0, 0, 0);
            }
        }

        // P2: softmax / bias -> transposed bf16 into wbuf.
        // C layout: col=l16+16*nt (s or d), row=quad*4+rr -> token = tw*16+quad*4+rr
        if (proj == 0) {
            float e[4][4];
            #pragma unroll
            for (int nt = 0; nt < 4; ++nt)
                #pragma unroll
                for (int rr = 0; rr < 4; ++rr)
                    e[nt][rr] = __expf((acc[nt][rr] + bcr[nt]) * invt);  // bounded arg, shift-free
            #pragma unroll
            for (int rr = 0; rr < 4; ++rr) {
                float s = e[0][rr] + e[1][rr] + e[2][rr] + e[3][rr];
                s += __shfl_xor(s, 1); s += __shfl_xor(s, 2);
                s += __shfl_xor(s, 4); s += __shfl_xor(s, 8);
                float inv = 1.0f / s;
                e[0][rr] *= inv; e[1][rr] *= inv; e[2][rr] *= inv; e[3][rr] *= inv;
            }
            #pragma unroll
            for (int nt = 0; nt < 4; ++nt) {
                normAcc[nt] += e[nt][0] + e[nt][1] + e[nt][2] + e[nt][3];
                uint2v p;
                p.x = pack2(e[nt][0], e[nt][1]);
                p.y = pack2(e[nt][2], e[nt][3]);
                *(uint2v*)(&wT[wbuf][(nt * 16 + l16) * MP + tw * 16 + quad * 4]) = p;
            }
        } else {
            #pragma unroll
            for (int nt = 0; nt < 4; ++nt) {
                uint2v p;
                p.x = pack2(acc[nt][0] + bfxr[nt], acc[nt][1] + bfxr[nt]);
                p.y = pack2(acc[nt][2] + bfxr[nt], acc[nt][3] + bfxr[nt]);
                *(uint2v*)(&fT[wbuf][(nt * 16 + l16) * MP + tw * 16 + quad * 4]) = p;
            }
        }

        __syncthreads();   // single barrier per chunk
    }

    // final P3 on the last written buffer (chunk 7 -> buf 1)
    {
        short8 a = *(const short8*)(&wT[1][(wv * 16 + l16) * MP + quad * 8]);
        #pragma unroll
        for (int nt = 0; nt < 4; ++nt) {
            short8 bf = *(const short8*)(&fT[1][(nt * 16 + l16) * MP + quad * 8]);
            Tac[nt] = __builtin_amdgcn_mfma_f32_16x16x32_bf16(a, bf, Tac[nt], 0, 0, 0);
        }
    }

    // epilogue: atomics into global accumulators
    const int basehs = (batch * 8 + head) * 64;
    #pragma unroll
    for (int nt = 0; nt < 4; ++nt) {
        #pragma unroll
        for (int rr = 0; rr < 4; ++rr) {
            int s = wv * 16 + quad * 4 + rr;
            int d = nt * 16 + l16;
            atomicAdd(&Tg[(basehs + s) * 64 + d], Tac[nt][rr]);
        }
    }
    if (proj == 0) {
        #pragma unroll
        for (int nt = 0; nt < 4; ++nt) {
            float v = normAcc[nt];
            v += __shfl_xor(v, 16);
            v += __shfl_xor(v, 32);
            if (quad == 0) atomicAdd(&ng[basehs + nt * 16 + l16], v);
        }
    }
}

// ================= Round-1 fallback path (known-correct, small-ws only) =================

__global__ void msfe_prep(const float* __restrict__ Wx, const float* __restrict__ bx,
                          const float* __restrict__ Wfx,
                          const float* __restrict__ Wslice, const float* __restrict__ bslice,
                          unsigned short* __restrict__ Wt, float* __restrict__ bc) {
    int j = blockIdx.x;
    int c = threadIdx.x;
    if (j < 512) {
        int h = j >> 6, s = j & 63;
        float acc = 0.f;
        #pragma unroll 8
        for (int d = 0; d < 64; ++d)
            acc += Wx[c * 512 + h * 64 + d] * Wslice[d * 64 + s];
        Wt[j * 256 + c] = f2bf(acc);
        if (c == 0) {
            float b = bslice[s];
            for (int d = 0; d < 64; ++d) b += bx[h * 64 + d] * Wslice[d * 64 + s];
            bc[j] = b;
        }
    } else {
        int col = j - 512;
        Wt[j * 256 + c] = f2bf(Wfx[c * 512 + col]);
    }
}

__global__ __launch_bounds__(512, 2)
void msfe_main(const float* __restrict__ x,
               const unsigned short* __restrict__ Wt,
               const float* __restrict__ bc,
               const float* __restrict__ bfx,
               const float* __restrict__ temperature,
               float* __restrict__ Tg, float* __restrict__ ng) {
    __shared__ unsigned short Ws[128 * WPITCH];
    __shared__ unsigned short Xs[64 * WPITCH];
    __shared__ unsigned short wT[64 * TPITCH];
    __shared__ unsigned short fT[64 * TPITCH];

    const int tid  = threadIdx.x;
    const int lane = tid & 63;
    const int wv   = tid >> 6;
    const int quad = lane >> 4;
    const int l16  = lane & 15;

    const int bidx = blockIdx.x;
    const int c8   = bidx & 7;
    const int ti   = (bidx >> 3) & 3;
    const int head = (bidx >> 5) & 7;
    const int rnd  = bidx >> 8;
    const int tile = rnd * 32 + c8 * 4 + ti;
    const int batch = tile >> 7;
    const long tok0 = (long)tile * 512;

    {
        int rr = tid & 127;
        int part = tid >> 7;
        int grow = (rr < 64) ? (head * 64 + rr) : (512 + head * 64 + (rr - 64));
        const short4v* src = (const short4v*)(Wt + grow * 256 + part * 64);
        short4v* dst = (short4v*)(Ws + rr * WPITCH + part * 64);
        #pragma unroll
        for (int j = 0; j < 16; ++j) dst[j] = src[j];
    }
    {
        const float4v* xg = (const float4v*)(x + tok0 * 256);
        #pragma unroll
        for (int i = 0; i < 8; ++i) {
            float4v v = xg[tid + i * 512];
            int f = (tid + i * 512) * 4;
            int trow = f >> 8, col = f & 255;
            short4v p;
            p.x = (short)f2bf(v.x); p.y = (short)f2bf(v.y);
            p.z = (short)f2bf(v.z); p.w = (short)f2bf(v.w);
            *(short4v*)(Xs + trow * WPITCH + col) = p;
        }
    }

    float bcr[4], bfxr[4];
    #pragma unroll
    for (int nt = 0; nt < 4; ++nt) {
        bcr[nt]  = bc [head * 64 + nt * 16 + l16];
        bfxr[nt] = bfx[head * 64 + nt * 16 + l16];
    }
    float tmp = temperature[head];
    tmp = fminf(fmaxf(tmp, 0.5f), 5.0f);
    const float invt = 1.0f / tmp;

    float4v Tac[2];
    Tac[0] = (float4v){0.f, 0.f, 0.f, 0.f};
    Tac[1] = (float4v){0.f, 0.f, 0.f, 0.f};
    float normAcc[4] = {0.f, 0.f, 0.f, 0.f};

    const int proj = wv >> 2;
    const int tw   = wv & 3;
    const int sh   = wv & 3;
    const int dh   = wv >> 2;

    __syncthreads();

    for (int c = 0; c < 8; ++c) {
        float4v xr[8];
        if (c < 7) {
            const float4v* xg = (const float4v*)(x + (tok0 + (long)(c + 1) * 64) * 256);
            #pragma unroll
            for (int i = 0; i < 8; ++i) xr[i] = xg[tid + i * 512];
        }

        float4v acc[4];
        #pragma unroll
        for (int nt = 0; nt < 4; ++nt) acc[nt] = (float4v){0.f, 0.f, 0.f, 0.f};
        #pragma unroll
        for (int ks = 0; ks < 8; ++ks) {
            short8 a = *(const short8*)(Xs + (tw * 16 + l16) * WPITCH + ks * 32 + quad * 8);
            #pragma unroll
            for (int nt = 0; nt < 4; ++nt) {
                short8 b = *(const short8*)(Ws + (proj * 64 + nt * 16 + l16) * WPITCH + ks * 32 + quad * 8);
                acc[nt] = __builtin_amdgcn_mfma_f32_16x16x32_bf16(a, b, acc[nt], 0, 0, 0);
            }
        }

        if (proj == 0) {
            float v[4][4];
            #pragma unroll
            for (int nt = 0; nt < 4; ++nt)
                #pragma unroll
                for (int rr = 0; rr < 4; ++rr)
                    v[nt][rr] = (acc[nt][rr] + bcr[nt]) * invt;
            #pragma unroll
            for (int rr = 0; rr < 4; ++rr) {
                float m = fmaxf(fmaxf(v[0][rr], v[1][rr]), fmaxf(v[2][rr], v[3][rr]));
                m = fmaxf(m, __shfl_xor(m, 1));
                m = fmaxf(m, __shfl_xor(m, 2));
                m = fmaxf(m, __shfl_xor(m, 4));
                m = fmaxf(m, __shfl_xor(m, 8));
                float e0 = __expf(v[0][rr] - m), e1 = __expf(v[1][rr] - m);
                float e2 = __expf(v[2][rr] - m), e3 = __expf(v[3][rr] - m);
                float s = e0 + e1 + e2 + e3;
                s += __shfl_xor(s, 1); s += __shfl_xor(s, 2);
                s += __shfl_xor(s, 4); s += __shfl_xor(s, 8);
                float inv = 1.0f / s;
                v[0][rr] = e0 * inv; v[1][rr] = e1 * inv; v[2][rr] = e2 * inv; v[3][rr] = e3 * inv;
            }
            #pragma unroll
            for (int nt = 0; nt < 4; ++nt) {
                normAcc[nt] += v[nt][0] + v[nt][1] + v[nt][2] + v[nt][3];
                short4v p;
                p.x = (short)f2bf(v[nt][0]); p.y = (short)f2bf(v[nt][1]);
                p.z = (short)f2bf(v[nt][2]); p.w = (short)f2bf(v[nt][3]);
                *(short4v*)(wT + (nt * 16 + l16) * TPITCH + tw * 16 + quad * 4) = p;
            }
        } else {
            #pragma unroll
            for (int nt = 0; nt < 4; ++nt) {
                short4v p;
                p.x = (short)f2bf(acc[nt][0] + bfxr[nt]);
                p.y = (short)f2bf(acc[nt][1] + bfxr[nt]);
                p.z = (short)f2bf(acc[nt][2] + bfxr[nt]);
                p.w = (short)f2bf(acc[nt][3] + bfxr[nt]);
                *(short4v*)(fT + (nt * 16 + l16) * TPITCH + tw * 16 + quad * 4) = p;
            }
        }

        __syncthreads();

        #pragma unroll
        for (int ks = 0; ks < 2; ++ks) {
            short8 a = *(const short8*)(wT + (sh * 16 + l16) * TPITCH + ks * 32 + quad * 8);
            #pragma unroll
            for (int nt = 0; nt < 2; ++nt) {
                short8 b = *(const short8*)(fT + (dh * 32 + nt * 16 + l16) * TPITCH + ks * 32 + quad * 8);
                Tac[nt] = __builtin_amdgcn_mfma_f32_16x16x32_bf16(a, b, Tac[nt], 0, 0, 0);
            }
        }

        if (c < 7) {
            #pragma unroll
            for (int i = 0; i < 8; ++i) {
                int f = tid * 4 + i * 2048;
                int trow = f >> 8, col = f & 255;
                short4v p;
                p.x = (short)f2bf(xr[i].x); p.y = (short)f2bf(xr[i].y);
                p.z = (short)f2bf(xr[i].z); p.w = (short)f2bf(xr[i].w);
                *(short4v*)(Xs + trow * WPITCH + col) = p;
            }
        }
        __syncthreads();
    }

    const int basehs = (batch * 8 + head) * 64;
    #pragma unroll
    for (int nt = 0; nt < 2; ++nt) {
        #pragma unroll
        for (int rr = 0; rr < 4; ++rr) {
            int s = sh * 16 + quad * 4 + rr;
            int d = dh * 32 + nt * 16 + l16;
            atomicAdd(&Tg[(basehs + s) * 64 + d], Tac[nt][rr]);
        }
    }
    if (wv < 4) {
        #pragma unroll
        for (int nt = 0; nt < 4; ++nt) {
            float v = normAcc[nt];
            v += __shfl_xor(v, 16);
            v += __shfl_xor(v, 32);
            if (quad == 0) atomicAdd(&ng[basehs + nt * 16 + l16], v);
        }
    }
}

// ---------------- finalize ----------------
__global__ void msfe_final(const float* __restrict__ Tg, const float* __restrict__ ng,
                           float* __restrict__ out) {
    int i = blockIdx.x * 256 + threadIdx.x;
    out[i] = Tg[i] / (ng[i >> 6] + 0.01f);
}

extern "C" void kernel_launch(void* const* d_in, const int* in_sizes, int n_in,
                              void* d_out, int out_size, void* d_ws, size_t ws_size,
                              hipStream_t stream) {
    const float* x       = (const float*)d_in[0];
    const float* Wx      = (const float*)d_in[1];
    const float* bx      = (const float*)d_in[2];
    const float* Wfx     = (const float*)d_in[3];
    const float* bfx     = (const float*)d_in[4];
    const float* Wslice  = (const float*)d_in[5];
    const float* bslice  = (const float*)d_in[6];
    const float* temp    = (const float*)d_in[7];

    char* ws = (char*)d_ws;
    const size_t NEED = 67901440;   // xf 64MB + WtF 512KB + bc 2KB + Tg 256KB + ng 4KB

    if (ws_size >= NEED) {
        unsigned short* xf  = (unsigned short*)ws;               // 67,108,864 B
        unsigned short* WtF = (unsigned short*)(ws + 67108864);  //    524,288 B
        float* bc = (float*)(ws + 67633152);                     //      2,048 B
        float* Tg = (float*)(ws + 67635200);                     //    262,144 B
        float* ng = (float*)(ws + 67897344);                     //      4,096 B

        hipMemsetAsync(Tg, 0, 262144 + 4096, stream);
        msfe_prep3<<<49, 256, 0, stream>>>(Wx, bx, Wfx, Wslice, bslice, WtF, bc);
        msfe_xprep<<<2048, 256, 0, stream>>>(x, xf);
        msfe_main3<<<4096, 256, 0, stream>>>(xf, WtF, bc, bfx, temp, Tg, ng);
        msfe_final<<<256, 256, 0, stream>>>(Tg, ng, (float*)d_out);
    } else {
        unsigned short* Wt = (unsigned short*)ws;       // 524,288 B
        float* bc = (float*)(ws + 524288);
        float* Tg = (float*)(ws + 526336);
        float* ng = (float*)(ws + 788480);

        hipMemsetAsync(Tg, 0, 262144 + 4096, stream);
        msfe_prep<<<1024, 256, 0, stream>>>(Wx, bx, Wfx, Wslice, bslice, Wt, bc);
        msfe_main<<<2048, 512, 0, stream>>>(x, Wt, bc, bfx, temp, Tg, ng);
        msfe_final<<<256, 256, 0, stream>>>(Tg, ng, (float*)d_out);
    }
}